// Round 8
// baseline (2619.406 us; speedup 1.0000x reference)
//
#include <hip/hip_runtime.h>

#define IN_CH 128
#define HID 64
#define BSHIFT 7
#define BNODES 128  // 1<<BSHIFT nodes per bucket; pack (dlocal<<17)|src needs N < 2^17

// ---------------- zero bucket counters ----------------
__global__ __launch_bounds__(256) void k_bzero(int* __restrict__ p, int n) {
  int i = blockIdx.x * 256 + threadIdx.x;
  if (i < n) p[i] = 0;
}

// ---------------- coarse bucket histogram ----------------
__global__ __launch_bounds__(256) void k_bhist(const int* __restrict__ dst,
                                               int* __restrict__ bCnt, int E) {
  int i = blockIdx.x * 256 + threadIdx.x;
  if (i < E) atomicAdd(&bCnt[dst[i] >> BSHIFT], 1);
}

// ---------------- exclusive scan of bucket counts (1 block, P <= 1024) ----------------
__global__ __launch_bounds__(1024) void k_bscan(const int* __restrict__ cnt,
                                                int* __restrict__ base, int P) {
  __shared__ int s[1024];
  const int tid = threadIdx.x;
  int v = (tid < P) ? cnt[tid] : 0;
  s[tid] = v;
  __syncthreads();
  for (int off = 1; off < 1024; off <<= 1) {
    int t = (tid >= off) ? s[tid - off] : 0;
    __syncthreads();
    s[tid] += t;
    __syncthreads();
  }
  if (tid < P) base[tid] = s[tid] - v;   // exclusive
  if (tid == P - 1) base[P] = s[tid];    // total = E
}

// ---------------- pass1: coarse-bin edges as packed u32 ----------------
// Writes cluster per bucket region -> L2-resident tail lines fill completely.
__global__ __launch_bounds__(256) void k_pass1(const int* __restrict__ src,
    const int* __restrict__ dst, const int* __restrict__ bBase,
    int* __restrict__ bCur, unsigned* __restrict__ pairBuf, int E) {
  int i = blockIdx.x * 256 + threadIdx.x;
  if (i < E) {
    int d = dst[i];
    int b = d >> BSHIFT;
    int p = atomicAdd(&bCur[b], 1);
    pairBuf[bBase[b] + p] = ((unsigned)(d & (BNODES - 1)) << 17) | (unsigned)src[i];
  }
}

// ---------------- pass2: per-bucket local count + scan + scatter; emits rowptr/deg/dinv ----------------
__global__ __launch_bounds__(256) void k_pass2(const unsigned* __restrict__ pairBuf,
    const int* __restrict__ bBase, int* __restrict__ csr, int* __restrict__ rowptr,
    int* __restrict__ degInt, float* __restrict__ dinv, int N) {
  __shared__ int cnt[BNODES], pfx[BNODES], cur[BNODES];
  const int b = blockIdx.x;
  const int tid = threadIdx.x;
  const int e0 = bBase[b], e1 = bBase[b + 1];
  if (tid < BNODES) { cnt[tid] = 0; cur[tid] = 0; }
  __syncthreads();
  for (int i = e0 + tid; i < e1; i += 256)
    atomicAdd(&cnt[pairBuf[i] >> 17], 1);
  __syncthreads();
  if (tid < BNODES) pfx[tid] = cnt[tid];
  __syncthreads();
  for (int off = 1; off < BNODES; off <<= 1) {
    int t = (tid < BNODES && tid >= off) ? pfx[tid - off] : 0;
    __syncthreads();
    if (tid < BNODES) pfx[tid] += t;
    __syncthreads();
  }
  if (tid < BNODES) {
    int node = (b << BSHIFT) + tid;
    int ex = pfx[tid] - cnt[tid];
    pfx[tid] = ex;  // store exclusive prefix for the scatter
    if (node < N) {
      rowptr[node] = e0 + ex;
      degInt[node] = cnt[tid];
      dinv[node]   = 1.0f / sqrtf((float)cnt[tid] + 1.0f);  // +1 self-loop
    }
  }
  __syncthreads();
  for (int i = e0 + tid; i < e1; i += 256) {
    unsigned u = pairBuf[i];
    int dl = u >> 17;
    int s  = (int)(u & 0x1FFFFu);
    int p = atomicAdd(&cur[dl], 1);
    csr[e0 + pfx[dl] + p] = s;  // contiguous ~16KB region per block: L2-hot
  }
}

// ---------------- layer-1 GEMM: g1 = (x @ W1) * dinv ----------------
// block = 256 threads, 64 nodes per block. Per wave: 16 nodes.
__global__ __launch_bounds__(256) void k_gemm1(const float* __restrict__ x,
    const float* __restrict__ W1, const float* __restrict__ dinv,
    float* __restrict__ g1, int N) {
  __shared__ __align__(16) float Ws[IN_CH * HID];  // 32 KB, [k][ch]
  __shared__ __align__(16) float xs[64 * IN_CH];   // 32 KB, col XOR-swizzled by (row&3)
  const int tid = threadIdx.x;
  const int base = blockIdx.x * 64;
  for (int i = tid; i < IN_CH * HID; i += 256) Ws[i] = W1[i];
  for (int i = tid; i < 64 * IN_CH; i += 256) {
    int row = i >> 7, col = i & 127;
    int n = base + row; if (n > N - 1) n = N - 1;
    xs[(row << 7) + (col ^ (row & 3))] = x[(size_t)n * IN_CH + col];
  }
  __syncthreads();
  const int w = tid >> 6, lane = tid & 63;
  const int ng = lane >> 4, cg = lane & 15;
  float acc[4][4];
  #pragma unroll
  for (int j = 0; j < 4; ++j)
    #pragma unroll
    for (int c = 0; c < 4; ++c) acc[j][c] = 0.f;
  #pragma unroll 8
  for (int k = 0; k < IN_CH; ++k) {
    float4 wv = *(const float4*)&Ws[(k << 6) + (cg << 2)];
    #pragma unroll
    for (int j = 0; j < 4; ++j) {
      int row = w * 16 + j * 4 + ng;              // row & 3 == ng
      float xv = xs[(row << 7) + (k ^ ng)];
      acc[j][0] = fmaf(xv, wv.x, acc[j][0]);
      acc[j][1] = fmaf(xv, wv.y, acc[j][1]);
      acc[j][2] = fmaf(xv, wv.z, acc[j][2]);
      acc[j][3] = fmaf(xv, wv.w, acc[j][3]);
    }
  }
  #pragma unroll
  for (int j = 0; j < 4; ++j) {
    int node = base + w * 16 + j * 4 + ng;
    if (node < N) {
      float di = dinv[node];
      float4 gv;
      gv.x = acc[j][0] * di; gv.y = acc[j][1] * di;
      gv.z = acc[j][2] * di; gv.w = acc[j][3] * di;
      *(float4*)&g1[(size_t)node * HID + (cg << 2)] = gv;
    }
  }
}

// ---------------- layer-2 GEMM: v = acc1*dinv + b1 ; g2 = (v @ W2)*dinv ----------------
__global__ __launch_bounds__(256) void k_gemm2(const float* __restrict__ accIn,
    const float* __restrict__ W2, const float* __restrict__ b1,
    const float* __restrict__ dinv,
    float* __restrict__ g2, int N) {
  __shared__ __align__(16) float Ws[HID * HID];  // 16 KB
  __shared__ __align__(16) float vs[64 * HID];   // 16 KB, swizzled
  const int tid = threadIdx.x;
  const int base = blockIdx.x * 64;
  for (int i = tid; i < HID * HID; i += 256) Ws[i] = W2[i];
  for (int i = tid; i < 64 * HID; i += 256) {
    int row = i >> 6, col = i & 63;
    int n = base + row; if (n > N - 1) n = N - 1;
    float v = fmaf(accIn[(size_t)n * HID + col], dinv[n], b1[col]);
    vs[(row << 6) + (col ^ (row & 3))] = v;
  }
  __syncthreads();
  const int w = tid >> 6, lane = tid & 63;
  const int ng = lane >> 4, cg = lane & 15;
  float acc[4][4];
  #pragma unroll
  for (int j = 0; j < 4; ++j)
    #pragma unroll
    for (int c = 0; c < 4; ++c) acc[j][c] = 0.f;
  #pragma unroll 8
  for (int k = 0; k < HID; ++k) {
    float4 wv = *(const float4*)&Ws[(k << 6) + (cg << 2)];
    #pragma unroll
    for (int j = 0; j < 4; ++j) {
      int row = w * 16 + j * 4 + ng;
      float xv = vs[(row << 6) + (k ^ ng)];
      acc[j][0] = fmaf(xv, wv.x, acc[j][0]);
      acc[j][1] = fmaf(xv, wv.y, acc[j][1]);
      acc[j][2] = fmaf(xv, wv.z, acc[j][2]);
      acc[j][3] = fmaf(xv, wv.w, acc[j][3]);
    }
  }
  #pragma unroll
  for (int j = 0; j < 4; ++j) {
    int node = base + w * 16 + j * 4 + ng;
    if (node < N) {
      float di = dinv[node];
      float4 gv;
      gv.x = acc[j][0] * di; gv.y = acc[j][1] * di;
      gv.z = acc[j][2] * di; gv.w = acc[j][3] * di;
      *(float4*)&g2[(size_t)node * HID + (cg << 2)] = gv;
    }
  }
}

// ---------------- gather: out[n] = g[n] + sum_{s in N(n)} g[s]  (no atomics) ----------------
__global__ __launch_bounds__(256) void k_gather(const int* __restrict__ rowptr,
    const int* __restrict__ degInt, const int* __restrict__ csr,
    const float* __restrict__ g, float* __restrict__ out, int N) {
  const int lane = threadIdx.x & 63;
  const int wid = (blockIdx.x * 256 + threadIdx.x) >> 6;  // node id
  if (wid >= N) return;
  const int start = rowptr[wid];
  const int deg = degInt[wid];
  float sum = g[(size_t)wid * HID + lane];  // self-loop term
  for (int c = 0; c < deg; c += 64) {
    int rem = deg - c;
    int cnt = rem < 64 ? rem : 64;
    int idx = 0;
    if (lane < cnt) idx = csr[start + c + lane];
    int j = 0;
    for (; j + 8 <= cnt; j += 8) {
      int s0 = __shfl(idx, j, 64);
      int s1 = __shfl(idx, j + 1, 64);
      int s2 = __shfl(idx, j + 2, 64);
      int s3 = __shfl(idx, j + 3, 64);
      int s4 = __shfl(idx, j + 4, 64);
      int s5 = __shfl(idx, j + 5, 64);
      int s6 = __shfl(idx, j + 6, 64);
      int s7 = __shfl(idx, j + 7, 64);
      float a0 = g[(size_t)s0 * HID + lane];
      float a1 = g[(size_t)s1 * HID + lane];
      float a2 = g[(size_t)s2 * HID + lane];
      float a3 = g[(size_t)s3 * HID + lane];
      float a4 = g[(size_t)s4 * HID + lane];
      float a5 = g[(size_t)s5 * HID + lane];
      float a6 = g[(size_t)s6 * HID + lane];
      float a7 = g[(size_t)s7 * HID + lane];
      sum += a0; sum += a1; sum += a2; sum += a3;
      sum += a4; sum += a5; sum += a6; sum += a7;
    }
    for (; j + 4 <= cnt; j += 4) {
      int s0 = __shfl(idx, j, 64);
      int s1 = __shfl(idx, j + 1, 64);
      int s2 = __shfl(idx, j + 2, 64);
      int s3 = __shfl(idx, j + 3, 64);
      float a0 = g[(size_t)s0 * HID + lane];
      float a1 = g[(size_t)s1 * HID + lane];
      float a2 = g[(size_t)s2 * HID + lane];
      float a3 = g[(size_t)s3 * HID + lane];
      sum += a0; sum += a1; sum += a2; sum += a3;
    }
    for (; j < cnt; ++j)
      sum += g[(size_t)__shfl(idx, j, 64) * HID + lane];
  }
  out[(size_t)wid * HID + lane] = sum;
}

// ---------------- MLP head ----------------
__global__ __launch_bounds__(256) void k_mlp(const float* __restrict__ accIn,
    const float* __restrict__ dinv, const float* __restrict__ b2,
    const float* __restrict__ lw1, const float* __restrict__ lb1,
    const float* __restrict__ lw2, const float* __restrict__ lb2,
    const float* __restrict__ lw3, const float* __restrict__ lb3,
    float* __restrict__ out, int N) {
  __shared__ __align__(16) float w1s[64 * 64];
  __shared__ __align__(16) float w2s[64 * 32];
  __shared__ float w3s[32], b2s[64], lb1s[64], lb2s[32];
  __shared__ float vls[4][64], t1ls[4][64];
  const int tid = threadIdx.x;
  for (int i = tid; i < 4096; i += 256) w1s[i] = lw1[i];
  for (int i = tid; i < 2048; i += 256) w2s[i] = lw2[i];
  if (tid < 64) { b2s[tid] = b2[tid]; lb1s[tid] = lb1[tid]; }
  if (tid < 32) { w3s[tid] = lw3[tid]; lb2s[tid] = lb2[tid]; }
  const float lb3v = lb3[0];
  __syncthreads();
  const int w = tid >> 6, lane = tid & 63;
  const int base = blockIdx.x * 16;
  for (int rep = 0; rep < 4; ++rep) {
    int nd = base + w * 4 + rep;
    int node = nd < N ? nd : N - 1;
    float di = dinv[node];
    float v = fmaf(accIn[(size_t)node * HID + lane], di, b2s[lane]);
    vls[w][lane] = v;
    __syncthreads();
    float t1 = lb1s[lane];
    #pragma unroll
    for (int k = 0; k < 64; ++k) t1 = fmaf(vls[w][k], w1s[(k << 6) + lane], t1);
    t1 = fmaxf(t1, 0.f);
    t1ls[w][lane] = t1;
    __syncthreads();
    const int l2 = lane & 31;
    float t2 = lb2s[l2];
    #pragma unroll
    for (int k = 0; k < 64; ++k) t2 = fmaf(t1ls[w][k], w2s[(k << 5) + l2], t2);
    t2 = fmaxf(t2, 0.f);
    float p = (lane < 32) ? t2 * w3s[l2] : 0.f;
    #pragma unroll
    for (int m = 1; m < 64; m <<= 1) p += __shfl_xor(p, m, 64);
    if (lane == 0 && nd < N) out[nd] = p + lb3v;
    __syncthreads();
  }
}

extern "C" void kernel_launch(void* const* d_in, const int* in_sizes, int n_in,
                              void* d_out, int out_size, void* d_ws, size_t ws_size,
                              hipStream_t stream) {
  const float* x   = (const float*)d_in[0];
  const int*   ei  = (const int*)d_in[1];
  const float* W1  = (const float*)d_in[2];
  const float* b1  = (const float*)d_in[3];
  const float* W2  = (const float*)d_in[4];
  const float* b2  = (const float*)d_in[5];
  const float* lw1 = (const float*)d_in[6];
  const float* lb1 = (const float*)d_in[7];
  const float* lw2 = (const float*)d_in[8];
  const float* lb2 = (const float*)d_in[9];
  const float* lw3 = (const float*)d_in[10];
  const float* lb3 = (const float*)d_in[11];
  float* out = (float*)d_out;

  const int N = in_sizes[0] / IN_CH;
  const int E = in_sizes[1] / 2;
  const int* src = ei;
  const int* dst = ei + E;
  const int P = (N + BNODES - 1) >> BSHIFT;  // 782 buckets (P <= 1024 required)

  auto align256 = [](size_t v) { return (v + 255) & ~(size_t)255; };
  char* ws = (char*)d_ws;
  size_t nB = align256((size_t)N * 4);
  float* dinv   = (float*)ws;  ws += nB;
  int*   degInt = (int*)ws;    ws += nB;
  int*   rowptr = (int*)ws;    ws += nB;
  int*   bCnt   = (int*)ws;                  // P ints
  int*   bCur   = bCnt + P;                  // P ints
  int*   bBase  = bCur + P;                  // P+1 ints
  ws += align256((size_t)(3 * P + 1) * 4);
  int*   csr    = (int*)ws;    ws += align256((size_t)E * 4);
  float* bufA   = (float*)ws;  ws += (size_t)N * HID * 4;  // g1 / g2
  float* bufB   = (float*)ws;                               // acc1 / acc2
  unsigned* pairBuf = (unsigned*)bufB;  // alias: dead before gather1 writes bufB

  const int nbE = (E + 255) / 256;
  const int gb  = (N + 63) / 64;
  const int gatherBlocks = (N * 64 + 255) / 256;

  // CSR build (two-level counting sort)
  hipLaunchKernelGGL(k_bzero, dim3((2 * P + 255) / 256), dim3(256), 0, stream, bCnt, 2 * P);
  hipLaunchKernelGGL(k_bhist, dim3(nbE), dim3(256), 0, stream, dst, bCnt, E);
  hipLaunchKernelGGL(k_bscan, dim3(1), dim3(1024), 0, stream, bCnt, bBase, P);
  hipLaunchKernelGGL(k_pass1, dim3(nbE), dim3(256), 0, stream, src, dst, bBase, bCur, pairBuf, E);
  hipLaunchKernelGGL(k_pass2, dim3(P), dim3(256), 0, stream, pairBuf, bBase,
                     csr, rowptr, degInt, dinv, N);

  // GCN layer 1
  hipLaunchKernelGGL(k_gemm1, dim3(gb), dim3(256), 0, stream, x, W1, dinv, bufA, N);
  hipLaunchKernelGGL(k_gather, dim3(gatherBlocks), dim3(256), 0, stream,
                     rowptr, degInt, csr, bufA, bufB, N);
  // GCN layer 2
  hipLaunchKernelGGL(k_gemm2, dim3(gb), dim3(256), 0, stream, bufB, W2, b1, dinv, bufA, N);
  hipLaunchKernelGGL(k_gather, dim3(gatherBlocks), dim3(256), 0, stream,
                     rowptr, degInt, csr, bufA, bufB, N);
  // MLP head
  hipLaunchKernelGGL(k_mlp, dim3((N + 15) / 16), dim3(256), 0, stream,
                     bufB, dinv, b2, lw1, lb1, lw2, lb2, lw3, lb3, out, N);
}

// Round 9
// 598.052 us; speedup vs baseline: 4.3799x; 4.3799x over previous
//
#include <hip/hip_runtime.h>

#define IN_CH 128
#define HID 64
#define TILE 8192     // edges per partition block (NBLK = ceil(E/TILE) must be <= 512)
#define B2SHIFT 10
#define B2NODES 1024  // nodes per bucket; pack (dlocal<<17)|src needs N < 2^17

// ---------------- per-block bucket histogram (LDS, no global atomics) ----------------
__global__ __launch_bounds__(256) void k_hist1(const int* __restrict__ dst,
                                               int* __restrict__ H, int E, int P) {
  __shared__ int cnt[1024];
  const int tid = threadIdx.x;
  for (int i = tid; i < P; i += 256) cnt[i] = 0;
  __syncthreads();
  const int base = blockIdx.x * TILE;
  const int end = min(base + TILE, E);
  for (int i = base + tid; i < end; i += 256)
    atomicAdd(&cnt[dst[i] >> B2SHIFT], 1);
  __syncthreads();
  for (int i = tid; i < P; i += 256) H[blockIdx.x * P + i] = cnt[i];
}

// ---------------- column scan: per-bucket exclusive prefix over blocks ----------------
__global__ __launch_bounds__(256) void k_colscan(const int* __restrict__ H,
    int* __restrict__ Orel, int* __restrict__ colTot, int P, int NBLK) {
  __shared__ int s[512];
  const int b = blockIdx.x, tid = threadIdx.x;
  const int iA = tid, iB = tid + 256;
  int origA = (iA < NBLK) ? H[iA * P + b] : 0;
  int origB = (iB < NBLK) ? H[iB * P + b] : 0;
  s[iA] = origA; s[iB] = origB;
  __syncthreads();
  for (int off = 1; off < 512; off <<= 1) {
    int tA = (iA >= off) ? s[iA - off] : 0;
    int tB = (iB >= off) ? s[iB - off] : 0;
    __syncthreads();
    s[iA] += tA; s[iB] += tB;
    __syncthreads();
  }
  if (iA < NBLK) Orel[iA * P + b] = s[iA] - origA;
  if (iB < NBLK) Orel[iB * P + b] = s[iB] - origB;
  if (tid == 255) colTot[b] = s[511];
}

// ---------------- bucket bases: exclusive scan of column totals (1 block) ----------------
__global__ __launch_bounds__(128) void k_bbase(const int* __restrict__ colTot,
                                               int* __restrict__ bBase, int P) {
  __shared__ int s[128];
  const int tid = threadIdx.x;
  int v = (tid < P) ? colTot[tid] : 0;
  s[tid] = v;
  __syncthreads();
  for (int off = 1; off < 128; off <<= 1) {
    int t = (tid >= off) ? s[tid - off] : 0;
    __syncthreads();
    s[tid] += t;
    __syncthreads();
  }
  if (tid < P) bBase[tid] = s[tid] - v;
  if (tid == P - 1) bBase[P] = s[tid];
}

// ---------------- partition: rank via LDS cursors, write dense per-(block,bucket) runs ----------------
__global__ __launch_bounds__(256) void k_pass1b(const int* __restrict__ src,
    const int* __restrict__ dst, const int* __restrict__ Orel,
    const int* __restrict__ bBase, unsigned* __restrict__ pairBuf, int E, int P) {
  __shared__ int off[1024], cur[1024];
  const int tid = threadIdx.x;
  for (int i = tid; i < P; i += 256) {
    off[i] = bBase[i] + Orel[blockIdx.x * P + i];
    cur[i] = 0;
  }
  __syncthreads();
  const int base = blockIdx.x * TILE;
  const int end = min(base + TILE, E);
  for (int i = base + tid; i < end; i += 256) {
    int d = dst[i];
    int b = d >> B2SHIFT;
    int r = atomicAdd(&cur[b], 1);  // LDS atomic: per-CU, ~84 ops/counter
    pairBuf[off[b] + r] = ((unsigned)(d & (B2NODES - 1)) << 17) | (unsigned)src[i];
  }
}

// ---------------- per-bucket CSR finalize: hist + scan + emit + scatter ----------------
__global__ __launch_bounds__(256) void k_pass2(const unsigned* __restrict__ pairBuf,
    const int* __restrict__ bBase, int* __restrict__ csr, int* __restrict__ rowptr,
    int* __restrict__ degInt, float* __restrict__ dinv, int N) {
  __shared__ int cnt[B2NODES], pfx[B2NODES], cur[B2NODES];
  __shared__ int lsum[256];
  const int b = blockIdx.x, tid = threadIdx.x;
  const int e0 = bBase[b], e1 = bBase[b + 1];
  for (int i = tid; i < B2NODES; i += 256) { cnt[i] = 0; cur[i] = 0; }
  __syncthreads();
  for (int i = e0 + tid; i < e1; i += 256)
    atomicAdd(&cnt[pairBuf[i] >> 17], 1);
  __syncthreads();
  int v[4], tsum = 0;
  #pragma unroll
  for (int k = 0; k < 4; ++k) { v[k] = cnt[tid * 4 + k]; tsum += v[k]; }
  lsum[tid] = tsum;
  __syncthreads();
  for (int off = 1; off < 256; off <<= 1) {
    int t = (tid >= off) ? lsum[tid - off] : 0;
    __syncthreads();
    lsum[tid] += t;
    __syncthreads();
  }
  int run = lsum[tid] - tsum;
  #pragma unroll
  for (int k = 0; k < 4; ++k) { pfx[tid * 4 + k] = run; run += v[k]; }
  __syncthreads();
  #pragma unroll
  for (int k = 0; k < 4; ++k) {
    int l = tid * 4 + k;
    int node = (b << B2SHIFT) + l;
    if (node < N) {
      rowptr[node] = e0 + pfx[l];
      degInt[node] = cnt[l];
      dinv[node]   = 1.0f / sqrtf((float)cnt[l] + 1.0f);  // +1 self-loop
    }
  }
  __syncthreads();
  for (int i = e0 + tid; i < e1; i += 256) {
    unsigned u = pairBuf[i];
    int dl = u >> 17;
    int r = atomicAdd(&cur[dl], 1);
    csr[e0 + pfx[dl] + r] = (int)(u & 0x1FFFFu);  // contiguous 131KB region: L2-dense
  }
}

// ---------------- layer-1 GEMM: g1 = (x @ W1) * dinv ----------------
__global__ __launch_bounds__(256) void k_gemm1(const float* __restrict__ x,
    const float* __restrict__ W1, const float* __restrict__ dinv,
    float* __restrict__ g1, int N) {
  __shared__ __align__(16) float Ws[IN_CH * HID];
  __shared__ __align__(16) float xs[64 * IN_CH];
  const int tid = threadIdx.x;
  const int base = blockIdx.x * 64;
  for (int i = tid; i < IN_CH * HID; i += 256) Ws[i] = W1[i];
  for (int i = tid; i < 64 * IN_CH; i += 256) {
    int row = i >> 7, col = i & 127;
    int n = base + row; if (n > N - 1) n = N - 1;
    xs[(row << 7) + (col ^ (row & 3))] = x[(size_t)n * IN_CH + col];
  }
  __syncthreads();
  const int w = tid >> 6, lane = tid & 63;
  const int ng = lane >> 4, cg = lane & 15;
  float acc[4][4];
  #pragma unroll
  for (int j = 0; j < 4; ++j)
    #pragma unroll
    for (int c = 0; c < 4; ++c) acc[j][c] = 0.f;
  #pragma unroll 8
  for (int k = 0; k < IN_CH; ++k) {
    float4 wv = *(const float4*)&Ws[(k << 6) + (cg << 2)];
    #pragma unroll
    for (int j = 0; j < 4; ++j) {
      int row = w * 16 + j * 4 + ng;
      float xv = xs[(row << 7) + (k ^ ng)];
      acc[j][0] = fmaf(xv, wv.x, acc[j][0]);
      acc[j][1] = fmaf(xv, wv.y, acc[j][1]);
      acc[j][2] = fmaf(xv, wv.z, acc[j][2]);
      acc[j][3] = fmaf(xv, wv.w, acc[j][3]);
    }
  }
  #pragma unroll
  for (int j = 0; j < 4; ++j) {
    int node = base + w * 16 + j * 4 + ng;
    if (node < N) {
      float di = dinv[node];
      float4 gv;
      gv.x = acc[j][0] * di; gv.y = acc[j][1] * di;
      gv.z = acc[j][2] * di; gv.w = acc[j][3] * di;
      *(float4*)&g1[(size_t)node * HID + (cg << 2)] = gv;
    }
  }
}

// ---------------- layer-2 GEMM ----------------
__global__ __launch_bounds__(256) void k_gemm2(const float* __restrict__ accIn,
    const float* __restrict__ W2, const float* __restrict__ b1,
    const float* __restrict__ dinv,
    float* __restrict__ g2, int N) {
  __shared__ __align__(16) float Ws[HID * HID];
  __shared__ __align__(16) float vs[64 * HID];
  const int tid = threadIdx.x;
  const int base = blockIdx.x * 64;
  for (int i = tid; i < HID * HID; i += 256) Ws[i] = W2[i];
  for (int i = tid; i < 64 * HID; i += 256) {
    int row = i >> 6, col = i & 63;
    int n = base + row; if (n > N - 1) n = N - 1;
    float v = fmaf(accIn[(size_t)n * HID + col], dinv[n], b1[col]);
    vs[(row << 6) + (col ^ (row & 3))] = v;
  }
  __syncthreads();
  const int w = tid >> 6, lane = tid & 63;
  const int ng = lane >> 4, cg = lane & 15;
  float acc[4][4];
  #pragma unroll
  for (int j = 0; j < 4; ++j)
    #pragma unroll
    for (int c = 0; c < 4; ++c) acc[j][c] = 0.f;
  #pragma unroll 8
  for (int k = 0; k < HID; ++k) {
    float4 wv = *(const float4*)&Ws[(k << 6) + (cg << 2)];
    #pragma unroll
    for (int j = 0; j < 4; ++j) {
      int row = w * 16 + j * 4 + ng;
      float xv = vs[(row << 6) + (k ^ ng)];
      acc[j][0] = fmaf(xv, wv.x, acc[j][0]);
      acc[j][1] = fmaf(xv, wv.y, acc[j][1]);
      acc[j][2] = fmaf(xv, wv.z, acc[j][2]);
      acc[j][3] = fmaf(xv, wv.w, acc[j][3]);
    }
  }
  #pragma unroll
  for (int j = 0; j < 4; ++j) {
    int node = base + w * 16 + j * 4 + ng;
    if (node < N) {
      float di = dinv[node];
      float4 gv;
      gv.x = acc[j][0] * di; gv.y = acc[j][1] * di;
      gv.z = acc[j][2] * di; gv.w = acc[j][3] * di;
      *(float4*)&g2[(size_t)node * HID + (cg << 2)] = gv;
    }
  }
}

// ---------------- gather: out[n] = g[n] + sum_{s in N(n)} g[s] ----------------
__global__ __launch_bounds__(256) void k_gather(const int* __restrict__ rowptr,
    const int* __restrict__ degInt, const int* __restrict__ csr,
    const float* __restrict__ g, float* __restrict__ out, int N) {
  const int lane = threadIdx.x & 63;
  const int wid = (blockIdx.x * 256 + threadIdx.x) >> 6;
  if (wid >= N) return;
  const int start = rowptr[wid];
  const int deg = degInt[wid];
  float sum = g[(size_t)wid * HID + lane];
  for (int c = 0; c < deg; c += 64) {
    int rem = deg - c;
    int cnt = rem < 64 ? rem : 64;
    int idx = 0;
    if (lane < cnt) idx = csr[start + c + lane];
    int j = 0;
    for (; j + 8 <= cnt; j += 8) {
      int s0 = __shfl(idx, j, 64);
      int s1 = __shfl(idx, j + 1, 64);
      int s2 = __shfl(idx, j + 2, 64);
      int s3 = __shfl(idx, j + 3, 64);
      int s4 = __shfl(idx, j + 4, 64);
      int s5 = __shfl(idx, j + 5, 64);
      int s6 = __shfl(idx, j + 6, 64);
      int s7 = __shfl(idx, j + 7, 64);
      float a0 = g[(size_t)s0 * HID + lane];
      float a1 = g[(size_t)s1 * HID + lane];
      float a2 = g[(size_t)s2 * HID + lane];
      float a3 = g[(size_t)s3 * HID + lane];
      float a4 = g[(size_t)s4 * HID + lane];
      float a5 = g[(size_t)s5 * HID + lane];
      float a6 = g[(size_t)s6 * HID + lane];
      float a7 = g[(size_t)s7 * HID + lane];
      sum += a0; sum += a1; sum += a2; sum += a3;
      sum += a4; sum += a5; sum += a6; sum += a7;
    }
    for (; j + 4 <= cnt; j += 4) {
      int s0 = __shfl(idx, j, 64);
      int s1 = __shfl(idx, j + 1, 64);
      int s2 = __shfl(idx, j + 2, 64);
      int s3 = __shfl(idx, j + 3, 64);
      float a0 = g[(size_t)s0 * HID + lane];
      float a1 = g[(size_t)s1 * HID + lane];
      float a2 = g[(size_t)s2 * HID + lane];
      float a3 = g[(size_t)s3 * HID + lane];
      sum += a0; sum += a1; sum += a2; sum += a3;
    }
    for (; j < cnt; ++j)
      sum += g[(size_t)__shfl(idx, j, 64) * HID + lane];
  }
  out[(size_t)wid * HID + lane] = sum;
}

// ---------------- MLP head ----------------
__global__ __launch_bounds__(256) void k_mlp(const float* __restrict__ accIn,
    const float* __restrict__ dinv, const float* __restrict__ b2,
    const float* __restrict__ lw1, const float* __restrict__ lb1,
    const float* __restrict__ lw2, const float* __restrict__ lb2,
    const float* __restrict__ lw3, const float* __restrict__ lb3,
    float* __restrict__ out, int N) {
  __shared__ __align__(16) float w1s[64 * 64];
  __shared__ __align__(16) float w2s[64 * 32];
  __shared__ float w3s[32], b2s[64], lb1s[64], lb2s[32];
  __shared__ float vls[4][64], t1ls[4][64];
  const int tid = threadIdx.x;
  for (int i = tid; i < 4096; i += 256) w1s[i] = lw1[i];
  for (int i = tid; i < 2048; i += 256) w2s[i] = lw2[i];
  if (tid < 64) { b2s[tid] = b2[tid]; lb1s[tid] = lb1[tid]; }
  if (tid < 32) { w3s[tid] = lw3[tid]; lb2s[tid] = lb2[tid]; }
  const float lb3v = lb3[0];
  __syncthreads();
  const int w = tid >> 6, lane = tid & 63;
  const int base = blockIdx.x * 16;
  for (int rep = 0; rep < 4; ++rep) {
    int nd = base + w * 4 + rep;
    int node = nd < N ? nd : N - 1;
    float di = dinv[node];
    float v = fmaf(accIn[(size_t)node * HID + lane], di, b2s[lane]);
    vls[w][lane] = v;
    __syncthreads();
    float t1 = lb1s[lane];
    #pragma unroll
    for (int k = 0; k < 64; ++k) t1 = fmaf(vls[w][k], w1s[(k << 6) + lane], t1);
    t1 = fmaxf(t1, 0.f);
    t1ls[w][lane] = t1;
    __syncthreads();
    const int l2 = lane & 31;
    float t2 = lb2s[l2];
    #pragma unroll
    for (int k = 0; k < 64; ++k) t2 = fmaf(t1ls[w][k], w2s[(k << 5) + l2], t2);
    t2 = fmaxf(t2, 0.f);
    float p = (lane < 32) ? t2 * w3s[l2] : 0.f;
    #pragma unroll
    for (int m = 1; m < 64; m <<= 1) p += __shfl_xor(p, m, 64);
    if (lane == 0 && nd < N) out[nd] = p + lb3v;
    __syncthreads();
  }
}

extern "C" void kernel_launch(void* const* d_in, const int* in_sizes, int n_in,
                              void* d_out, int out_size, void* d_ws, size_t ws_size,
                              hipStream_t stream) {
  const float* x   = (const float*)d_in[0];
  const int*   ei  = (const int*)d_in[1];
  const float* W1  = (const float*)d_in[2];
  const float* b1  = (const float*)d_in[3];
  const float* W2  = (const float*)d_in[4];
  const float* b2  = (const float*)d_in[5];
  const float* lw1 = (const float*)d_in[6];
  const float* lb1 = (const float*)d_in[7];
  const float* lw2 = (const float*)d_in[8];
  const float* lb2 = (const float*)d_in[9];
  const float* lw3 = (const float*)d_in[10];
  const float* lb3 = (const float*)d_in[11];
  float* out = (float*)d_out;

  const int N = in_sizes[0] / IN_CH;
  const int E = in_sizes[1] / 2;
  const int* src = ei;
  const int* dst = ei + E;
  const int NBLK = (E + TILE - 1) / TILE;            // 391 (<= 512 required)
  const int P = (N + B2NODES - 1) >> B2SHIFT;        // 98 (<= 128 required)

  auto align256 = [](size_t v) { return (v + 255) & ~(size_t)255; };
  char* ws = (char*)d_ws;
  size_t nB = align256((size_t)N * 4);
  float* dinv   = (float*)ws;  ws += nB;
  int*   degInt = (int*)ws;    ws += nB;
  int*   rowptr = (int*)ws;    ws += nB;
  int*   H      = (int*)ws;    ws += align256((size_t)NBLK * P * 4);
  int*   Orel   = (int*)ws;    ws += align256((size_t)NBLK * P * 4);
  int*   colTot = (int*)ws;    ws += align256((size_t)P * 4);
  int*   bBase  = (int*)ws;    ws += align256((size_t)(P + 1) * 4);
  int*   csr    = (int*)ws;    ws += align256((size_t)E * 4);
  float* bufA   = (float*)ws;  ws += (size_t)N * HID * 4;  // g1 / g2
  float* bufB   = (float*)ws;                               // acc1 / acc2
  unsigned* pairBuf = (unsigned*)bufB;  // alias: dead before gather1 writes bufB

  const int gb  = (N + 63) / 64;
  const int gatherBlocks = (N * 64 + 255) / 256;

  // CSR build (radix partition, all contended atomics in LDS)
  hipLaunchKernelGGL(k_hist1,   dim3(NBLK), dim3(256), 0, stream, dst, H, E, P);
  hipLaunchKernelGGL(k_colscan, dim3(P), dim3(256), 0, stream, H, Orel, colTot, P, NBLK);
  hipLaunchKernelGGL(k_bbase,   dim3(1), dim3(128), 0, stream, colTot, bBase, P);
  hipLaunchKernelGGL(k_pass1b,  dim3(NBLK), dim3(256), 0, stream, src, dst, Orel, bBase, pairBuf, E, P);
  hipLaunchKernelGGL(k_pass2,   dim3(P), dim3(256), 0, stream, pairBuf, bBase,
                     csr, rowptr, degInt, dinv, N);

  // GCN layer 1
  hipLaunchKernelGGL(k_gemm1, dim3(gb), dim3(256), 0, stream, x, W1, dinv, bufA, N);
  hipLaunchKernelGGL(k_gather, dim3(gatherBlocks), dim3(256), 0, stream,
                     rowptr, degInt, csr, bufA, bufB, N);
  // GCN layer 2
  hipLaunchKernelGGL(k_gemm2, dim3(gb), dim3(256), 0, stream, bufB, W2, b1, dinv, bufA, N);
  hipLaunchKernelGGL(k_gather, dim3(gatherBlocks), dim3(256), 0, stream,
                     rowptr, degInt, csr, bufA, bufB, N);
  // MLP head
  hipLaunchKernelGGL(k_mlp, dim3((N + 15) / 16), dim3(256), 0, stream,
                     bufB, dinv, b2, lw1, lb1, lw2, lb2, lw3, lb3, out, N);
}

// Round 11
// 538.389 us; speedup vs baseline: 4.8653x; 1.1108x over previous
//
#include <hip/hip_runtime.h>

#define IN_CH 128
#define HID 64
#define TILE 8192     // edges per partition block (NBLK = ceil(E/TILE) must be <= 512)
#define B2SHIFT 10
#define B2NODES 1024  // nodes per bucket; pack (dlocal<<17)|src needs N < 2^17

// ---------------- per-block bucket histogram (LDS, no global atomics) ----------------
__global__ __launch_bounds__(256) void k_hist1(const int* __restrict__ dst,
                                               int* __restrict__ H, int E, int P) {
  __shared__ int cnt[1024];
  const int tid = threadIdx.x;
  for (int i = tid; i < P; i += 256) cnt[i] = 0;
  __syncthreads();
  const int base = blockIdx.x * TILE;
  const int end = min(base + TILE, E);
  for (int i = base + tid; i < end; i += 256)
    atomicAdd(&cnt[dst[i] >> B2SHIFT], 1);
  __syncthreads();
  for (int i = tid; i < P; i += 256) H[blockIdx.x * P + i] = cnt[i];
}

// ---------------- column scan: per-bucket exclusive prefix over blocks ----------------
__global__ __launch_bounds__(256) void k_colscan(const int* __restrict__ H,
    int* __restrict__ Orel, int* __restrict__ colTot, int P, int NBLK) {
  __shared__ int s[512];
  const int b = blockIdx.x, tid = threadIdx.x;
  const int iA = tid, iB = tid + 256;
  int origA = (iA < NBLK) ? H[iA * P + b] : 0;
  int origB = (iB < NBLK) ? H[iB * P + b] : 0;
  s[iA] = origA; s[iB] = origB;
  __syncthreads();
  for (int off = 1; off < 512; off <<= 1) {
    int tA = (iA >= off) ? s[iA - off] : 0;
    int tB = (iB >= off) ? s[iB - off] : 0;
    __syncthreads();
    s[iA] += tA; s[iB] += tB;
    __syncthreads();
  }
  if (iA < NBLK) Orel[iA * P + b] = s[iA] - origA;
  if (iB < NBLK) Orel[iB * P + b] = s[iB] - origB;
  if (tid == 255) colTot[b] = s[511];
}

// ---------------- bucket bases: exclusive scan of column totals (1 block) ----------------
__global__ __launch_bounds__(128) void k_bbase(const int* __restrict__ colTot,
                                               int* __restrict__ bBase, int P) {
  __shared__ int s[128];
  const int tid = threadIdx.x;
  int v = (tid < P) ? colTot[tid] : 0;
  s[tid] = v;
  __syncthreads();
  for (int off = 1; off < 128; off <<= 1) {
    int t = (tid >= off) ? s[tid - off] : 0;
    __syncthreads();
    s[tid] += t;
    __syncthreads();
  }
  if (tid < P) bBase[tid] = s[tid] - v;
  if (tid == P - 1) bBase[P] = s[tid];
}

// ---------------- partition: rank via LDS cursors, write dense per-(block,bucket) runs ----------------
__global__ __launch_bounds__(256) void k_pass1b(const int* __restrict__ src,
    const int* __restrict__ dst, const int* __restrict__ Orel,
    const int* __restrict__ bBase, unsigned* __restrict__ pairBuf, int E, int P) {
  __shared__ int off[1024], cur[1024];
  const int tid = threadIdx.x;
  for (int i = tid; i < P; i += 256) {
    off[i] = bBase[i] + Orel[blockIdx.x * P + i];
    cur[i] = 0;
  }
  __syncthreads();
  const int base = blockIdx.x * TILE;
  const int end = min(base + TILE, E);
  for (int i = base + tid; i < end; i += 256) {
    int d = dst[i];
    int b = d >> B2SHIFT;
    int r = atomicAdd(&cur[b], 1);  // LDS atomic: per-CU, low contention
    pairBuf[off[b] + r] = ((unsigned)(d & (B2NODES - 1)) << 17) | (unsigned)src[i];
  }
}

// ---------------- per-bucket CSR finalize: hist + scan + emit + scatter ----------------
__global__ __launch_bounds__(256) void k_pass2(const unsigned* __restrict__ pairBuf,
    const int* __restrict__ bBase, int* __restrict__ csr, int* __restrict__ rowptr,
    int* __restrict__ degInt, float* __restrict__ dinv, int N) {
  __shared__ int cnt[B2NODES], pfx[B2NODES], cur[B2NODES];
  __shared__ int lsum[256];
  const int b = blockIdx.x, tid = threadIdx.x;
  const int e0 = bBase[b], e1 = bBase[b + 1];
  for (int i = tid; i < B2NODES; i += 256) { cnt[i] = 0; cur[i] = 0; }
  __syncthreads();
  for (int i = e0 + tid; i < e1; i += 256)
    atomicAdd(&cnt[pairBuf[i] >> 17], 1);
  __syncthreads();
  int v[4], tsum = 0;
  #pragma unroll
  for (int k = 0; k < 4; ++k) { v[k] = cnt[tid * 4 + k]; tsum += v[k]; }
  lsum[tid] = tsum;
  __syncthreads();
  for (int off = 1; off < 256; off <<= 1) {
    int t = (tid >= off) ? lsum[tid - off] : 0;
    __syncthreads();
    lsum[tid] += t;
    __syncthreads();
  }
  int run = lsum[tid] - tsum;
  #pragma unroll
  for (int k = 0; k < 4; ++k) { pfx[tid * 4 + k] = run; run += v[k]; }
  __syncthreads();
  #pragma unroll
  for (int k = 0; k < 4; ++k) {
    int l = tid * 4 + k;
    int node = (b << B2SHIFT) + l;
    if (node < N) {
      rowptr[node] = e0 + pfx[l];
      degInt[node] = cnt[l];
      dinv[node]   = 1.0f / sqrtf((float)cnt[l] + 1.0f);  // +1 self-loop
    }
  }
  __syncthreads();
  for (int i = e0 + tid; i < e1; i += 256) {
    unsigned u = pairBuf[i];
    int dl = u >> 17;
    int r = atomicAdd(&cur[dl], 1);
    csr[e0 + pfx[dl] + r] = (int)(u & 0x1FFFFu);  // contiguous 131KB region: L2-dense
  }
}

// ---------------- layer-1 GEMM: g1 = (x @ W1) * dinv ----------------
__global__ __launch_bounds__(256) void k_gemm1(const float* __restrict__ x,
    const float* __restrict__ W1, const float* __restrict__ dinv,
    float* __restrict__ g1, int N) {
  __shared__ __align__(16) float Ws[IN_CH * HID];
  __shared__ __align__(16) float xs[64 * IN_CH];
  const int tid = threadIdx.x;
  const int base = blockIdx.x * 64;
  for (int i = tid; i < IN_CH * HID; i += 256) Ws[i] = W1[i];
  for (int i = tid; i < 64 * IN_CH; i += 256) {
    int row = i >> 7, col = i & 127;
    int n = base + row; if (n > N - 1) n = N - 1;
    xs[(row << 7) + (col ^ (row & 3))] = x[(size_t)n * IN_CH + col];
  }
  __syncthreads();
  const int w = tid >> 6, lane = tid & 63;
  const int ng = lane >> 4, cg = lane & 15;
  float acc[4][4];
  #pragma unroll
  for (int j = 0; j < 4; ++j)
    #pragma unroll
    for (int c = 0; c < 4; ++c) acc[j][c] = 0.f;
  #pragma unroll 8
  for (int k = 0; k < IN_CH; ++k) {
    float4 wv = *(const float4*)&Ws[(k << 6) + (cg << 2)];
    #pragma unroll
    for (int j = 0; j < 4; ++j) {
      int row = w * 16 + j * 4 + ng;
      float xv = xs[(row << 7) + (k ^ ng)];
      acc[j][0] = fmaf(xv, wv.x, acc[j][0]);
      acc[j][1] = fmaf(xv, wv.y, acc[j][1]);
      acc[j][2] = fmaf(xv, wv.z, acc[j][2]);
      acc[j][3] = fmaf(xv, wv.w, acc[j][3]);
    }
  }
  #pragma unroll
  for (int j = 0; j < 4; ++j) {
    int node = base + w * 16 + j * 4 + ng;
    if (node < N) {
      float di = dinv[node];
      float4 gv;
      gv.x = acc[j][0] * di; gv.y = acc[j][1] * di;
      gv.z = acc[j][2] * di; gv.w = acc[j][3] * di;
      *(float4*)&g1[(size_t)node * HID + (cg << 2)] = gv;
    }
  }
}

// ---------------- layer-2 GEMM ----------------
__global__ __launch_bounds__(256) void k_gemm2(const float* __restrict__ accIn,
    const float* __restrict__ W2, const float* __restrict__ b1,
    const float* __restrict__ dinv,
    float* __restrict__ g2, int N) {
  __shared__ __align__(16) float Ws[HID * HID];
  __shared__ __align__(16) float vs[64 * HID];
  const int tid = threadIdx.x;
  const int base = blockIdx.x * 64;
  for (int i = tid; i < HID * HID; i += 256) Ws[i] = W2[i];
  for (int i = tid; i < 64 * HID; i += 256) {
    int row = i >> 6, col = i & 63;
    int n = base + row; if (n > N - 1) n = N - 1;
    float v = fmaf(accIn[(size_t)n * HID + col], dinv[n], b1[col]);
    vs[(row << 6) + (col ^ (row & 3))] = v;
  }
  __syncthreads();
  const int w = tid >> 6, lane = tid & 63;
  const int ng = lane >> 4, cg = lane & 15;
  float acc[4][4];
  #pragma unroll
  for (int j = 0; j < 4; ++j)
    #pragma unroll
    for (int c = 0; c < 4; ++c) acc[j][c] = 0.f;
  #pragma unroll 8
  for (int k = 0; k < HID; ++k) {
    float4 wv = *(const float4*)&Ws[(k << 6) + (cg << 2)];
    #pragma unroll
    for (int j = 0; j < 4; ++j) {
      int row = w * 16 + j * 4 + ng;
      float xv = vs[(row << 6) + (k ^ ng)];
      acc[j][0] = fmaf(xv, wv.x, acc[j][0]);
      acc[j][1] = fmaf(xv, wv.y, acc[j][1]);
      acc[j][2] = fmaf(xv, wv.z, acc[j][2]);
      acc[j][3] = fmaf(xv, wv.w, acc[j][3]);
    }
  }
  #pragma unroll
  for (int j = 0; j < 4; ++j) {
    int node = base + w * 16 + j * 4 + ng;
    if (node < N) {
      float di = dinv[node];
      float4 gv;
      gv.x = acc[j][0] * di; gv.y = acc[j][1] * di;
      gv.z = acc[j][2] * di; gv.w = acc[j][3] * di;
      *(float4*)&g2[(size_t)node * HID + (cg << 2)] = gv;
    }
  }
}

// ---------------- gather: out[n] = g[n] + sum_{s in N(n)} g[s] ----------------
__global__ __launch_bounds__(256) void k_gather(const int* __restrict__ rowptr,
    const int* __restrict__ degInt, const int* __restrict__ csr,
    const float* __restrict__ g, float* __restrict__ out, int N) {
  const int lane = threadIdx.x & 63;
  const int wid = (blockIdx.x * 256 + threadIdx.x) >> 6;
  if (wid >= N) return;
  const int start = rowptr[wid];
  const int deg = degInt[wid];
  float sum = g[(size_t)wid * HID + lane];
  for (int c = 0; c < deg; c += 64) {
    int rem = deg - c;
    int cnt = rem < 64 ? rem : 64;
    int idx = 0;
    if (lane < cnt) idx = csr[start + c + lane];
    int j = 0;
    for (; j + 8 <= cnt; j += 8) {
      int s0 = __shfl(idx, j, 64);
      int s1 = __shfl(idx, j + 1, 64);
      int s2 = __shfl(idx, j + 2, 64);
      int s3 = __shfl(idx, j + 3, 64);
      int s4 = __shfl(idx, j + 4, 64);
      int s5 = __shfl(idx, j + 5, 64);
      int s6 = __shfl(idx, j + 6, 64);
      int s7 = __shfl(idx, j + 7, 64);
      float a0 = g[(size_t)s0 * HID + lane];
      float a1 = g[(size_t)s1 * HID + lane];
      float a2 = g[(size_t)s2 * HID + lane];
      float a3 = g[(size_t)s3 * HID + lane];
      float a4 = g[(size_t)s4 * HID + lane];
      float a5 = g[(size_t)s5 * HID + lane];
      float a6 = g[(size_t)s6 * HID + lane];
      float a7 = g[(size_t)s7 * HID + lane];
      sum += a0; sum += a1; sum += a2; sum += a3;
      sum += a4; sum += a5; sum += a6; sum += a7;
    }
    for (; j + 4 <= cnt; j += 4) {
      int s0 = __shfl(idx, j, 64);
      int s1 = __shfl(idx, j + 1, 64);
      int s2 = __shfl(idx, j + 2, 64);
      int s3 = __shfl(idx, j + 3, 64);
      float a0 = g[(size_t)s0 * HID + lane];
      float a1 = g[(size_t)s1 * HID + lane];
      float a2 = g[(size_t)s2 * HID + lane];
      float a3 = g[(size_t)s3 * HID + lane];
      sum += a0; sum += a1; sum += a2; sum += a3;
    }
    for (; j < cnt; ++j)
      sum += g[(size_t)__shfl(idx, j, 64) * HID + lane];
  }
  out[(size_t)wid * HID + lane] = sum;
}

// ---------------- MLP head (GEMM-style, 64 nodes/block, fused 3 layers) ----------------
// layer1 64x64: 4x4 reg tile; layer2 64x32: 4x2 reg tile; layer3: shfl_xor reduce.
__global__ __launch_bounds__(256) void k_mlp(const float* __restrict__ accIn,
    const float* __restrict__ dinv, const float* __restrict__ b2,
    const float* __restrict__ lw1, const float* __restrict__ lb1,
    const float* __restrict__ lw2, const float* __restrict__ lb2,
    const float* __restrict__ lw3, const float* __restrict__ lb3,
    float* __restrict__ out, int N) {
  __shared__ __align__(16) float w1s[64 * 64];   // 16 KB, [k][ch]
  __shared__ __align__(16) float w2s[64 * 32];   // 8 KB, [k][ch]
  __shared__ float w3s[32], lb1s[64], lb2s[32];
  __shared__ __align__(16) float vs[64 * 64];    // 16 KB, col XOR-swizzled by (row&3)
  __shared__ __align__(16) float t1s[64 * 64];   // 16 KB, swizzled
  const int tid = threadIdx.x;
  const int base = blockIdx.x * 64;
  for (int i = tid; i < 4096; i += 256) w1s[i] = lw1[i];
  for (int i = tid; i < 2048; i += 256) w2s[i] = lw2[i];
  if (tid < 64) lb1s[tid] = lb1[tid];
  if (tid < 32) { w3s[tid] = lw3[tid]; lb2s[tid] = lb2[tid]; }
  const float lb3v = lb3[0];
  // stage v = accIn*dinv + b2 (b2/dinv via L1/L2; coalesced accIn)
  for (int i = tid; i < 64 * 64; i += 256) {
    int row = i >> 6, col = i & 63;
    int n = base + row; if (n > N - 1) n = N - 1;
    vs[(row << 6) + (col ^ (row & 3))] = fmaf(accIn[(size_t)n * HID + col], dinv[n], b2[col]);
  }
  __syncthreads();
  const int w = tid >> 6, lane = tid & 63;
  const int ng = lane >> 4, cg = lane & 15;
  // ---- layer 1: t1 = relu(v @ lw1 + lb1) ----
  float acc[4][4];
  #pragma unroll
  for (int j = 0; j < 4; ++j)
    #pragma unroll
    for (int c = 0; c < 4; ++c) acc[j][c] = lb1s[(cg << 2) + c];
  #pragma unroll 8
  for (int k = 0; k < 64; ++k) {
    float4 wv = *(const float4*)&w1s[(k << 6) + (cg << 2)];
    #pragma unroll
    for (int j = 0; j < 4; ++j) {
      int row = w * 16 + j * 4 + ng;              // row & 3 == ng
      float xv = vs[(row << 6) + (k ^ ng)];
      acc[j][0] = fmaf(xv, wv.x, acc[j][0]);
      acc[j][1] = fmaf(xv, wv.y, acc[j][1]);
      acc[j][2] = fmaf(xv, wv.z, acc[j][2]);
      acc[j][3] = fmaf(xv, wv.w, acc[j][3]);
    }
  }
  #pragma unroll
  for (int j = 0; j < 4; ++j) {
    int row = w * 16 + j * 4 + ng;
    #pragma unroll
    for (int c = 0; c < 4; ++c)
      t1s[(row << 6) + (((cg << 2) + c) ^ ng)] = fmaxf(acc[j][c], 0.f);
  }
  __syncthreads();
  // ---- layer 2: t2 = relu(t1 @ lw2 + lb2), 4 nodes x 2 ch per thread ----
  float a2[4][2];
  #pragma unroll
  for (int j = 0; j < 4; ++j) {
    a2[j][0] = lb2s[(cg << 1)];
    a2[j][1] = lb2s[(cg << 1) + 1];
  }
  #pragma unroll 8
  for (int k = 0; k < 64; ++k) {
    float2 wv = *(const float2*)&w2s[(k << 5) + (cg << 1)];
    #pragma unroll
    for (int j = 0; j < 4; ++j) {
      int row = w * 16 + j * 4 + ng;
      float xv = t1s[(row << 6) + (k ^ ng)];
      a2[j][0] = fmaf(xv, wv.x, a2[j][0]);
      a2[j][1] = fmaf(xv, wv.y, a2[j][1]);
    }
  }
  // ---- layer 3: out = relu(t2) . w3 + lb3, reduce across 16 cg lanes ----
  const float w3a = w3s[(cg << 1)], w3b = w3s[(cg << 1) + 1];
  #pragma unroll
  for (int j = 0; j < 4; ++j) {
    float p = fmaxf(a2[j][0], 0.f) * w3a + fmaxf(a2[j][1], 0.f) * w3b;
    p += __shfl_xor(p, 1, 64);
    p += __shfl_xor(p, 2, 64);
    p += __shfl_xor(p, 4, 64);
    p += __shfl_xor(p, 8, 64);
    int node = base + w * 16 + j * 4 + ng;
    if (cg == 0 && node < N) out[node] = p + lb3v;
  }
}

extern "C" void kernel_launch(void* const* d_in, const int* in_sizes, int n_in,
                              void* d_out, int out_size, void* d_ws, size_t ws_size,
                              hipStream_t stream) {
  const float* x   = (const float*)d_in[0];
  const int*   ei  = (const int*)d_in[1];
  const float* W1  = (const float*)d_in[2];
  const float* b1  = (const float*)d_in[3];
  const float* W2  = (const float*)d_in[4];
  const float* b2  = (const float*)d_in[5];
  const float* lw1 = (const float*)d_in[6];
  const float* lb1 = (const float*)d_in[7];
  const float* lw2 = (const float*)d_in[8];
  const float* lb2 = (const float*)d_in[9];
  const float* lw3 = (const float*)d_in[10];
  const float* lb3 = (const float*)d_in[11];
  float* out = (float*)d_out;

  const int N = in_sizes[0] / IN_CH;
  const int E = in_sizes[1] / 2;
  const int* src = ei;
  const int* dst = ei + E;
  const int NBLK = (E + TILE - 1) / TILE;            // 391 (<= 512 required)
  const int P = (N + B2NODES - 1) >> B2SHIFT;        // 98 (<= 128 required)

  auto align256 = [](size_t v) { return (v + 255) & ~(size_t)255; };
  char* ws = (char*)d_ws;
  size_t nB = align256((size_t)N * 4);
  float* dinv   = (float*)ws;  ws += nB;
  int*   degInt = (int*)ws;    ws += nB;
  int*   rowptr = (int*)ws;    ws += nB;
  int*   H      = (int*)ws;    ws += align256((size_t)NBLK * P * 4);
  int*   Orel   = (int*)ws;    ws += align256((size_t)NBLK * P * 4);
  int*   colTot = (int*)ws;    ws += align256((size_t)P * 4);
  int*   bBase  = (int*)ws;    ws += align256((size_t)(P + 1) * 4);
  int*   csr    = (int*)ws;    ws += align256((size_t)E * 4);
  float* bufA   = (float*)ws;  ws += (size_t)N * HID * 4;  // g1 / g2
  float* bufB   = (float*)ws;                               // acc1 / acc2
  unsigned* pairBuf = (unsigned*)bufB;  // alias: dead before gather1 writes bufB

  const int gb  = (N + 63) / 64;
  const int gatherBlocks = (N * 64 + 255) / 256;

  // CSR build (radix partition, all contended atomics in LDS)
  hipLaunchKernelGGL(k_hist1,   dim3(NBLK), dim3(256), 0, stream, dst, H, E, P);
  hipLaunchKernelGGL(k_colscan, dim3(P), dim3(256), 0, stream, H, Orel, colTot, P, NBLK);
  hipLaunchKernelGGL(k_bbase,   dim3(1), dim3(128), 0, stream, colTot, bBase, P);
  hipLaunchKernelGGL(k_pass1b,  dim3(NBLK), dim3(256), 0, stream, src, dst, Orel, bBase, pairBuf, E, P);
  hipLaunchKernelGGL(k_pass2,   dim3(P), dim3(256), 0, stream, pairBuf, bBase,
                     csr, rowptr, degInt, dinv, N);

  // GCN layer 1
  hipLaunchKernelGGL(k_gemm1, dim3(gb), dim3(256), 0, stream, x, W1, dinv, bufA, N);
  hipLaunchKernelGGL(k_gather, dim3(gatherBlocks), dim3(256), 0, stream,
                     rowptr, degInt, csr, bufA, bufB, N);
  // GCN layer 2
  hipLaunchKernelGGL(k_gemm2, dim3(gb), dim3(256), 0, stream, bufB, W2, b1, dinv, bufA, N);
  hipLaunchKernelGGL(k_gather, dim3(gatherBlocks), dim3(256), 0, stream,
                     rowptr, degInt, csr, bufA, bufB, N);
  // MLP head (GEMM-style)
  hipLaunchKernelGGL(k_mlp, dim3(gb), dim3(256), 0, stream,
                     bufB, dinv, b2, lw1, lb1, lw2, lb2, lw3, lb3, out, N);
}